// Round 2
// baseline (135.152 us; speedup 1.0000x reference)
//
#include <hip/hip_runtime.h>

typedef __bf16 bf16x8 __attribute__((ext_vector_type(8)));
typedef __bf16 bf16x4 __attribute__((ext_vector_type(4)));
typedef float  f32x4  __attribute__((ext_vector_type(4)));

#define SCALE 0.08838834764831845f

__device__ __forceinline__ f32x4 mfma16(bf16x8 a, bf16x8 b, f32x4 c) {
  return __builtin_amdgcn_mfma_f32_16x16x32_bf16(a, b, c, 0, 0, 0);
}

// stage a [64][128] fp32 block into LDS as bf16 [64][136] (512 threads)
__device__ __forceinline__ void stage64x128(const float* __restrict__ src,
                                            __bf16 (*dst)[136], int tid) {
  const int row  = tid >> 3;
  const int colb = (tid & 7) << 4;
  const float4* s4 = (const float4*)(src + (size_t)row * 128 + colb);
  float4 f0 = s4[0], f1 = s4[1], f2 = s4[2], f3 = s4[3];
  bf16x8 lo, hi;
  lo[0] = (__bf16)f0.x; lo[1] = (__bf16)f0.y; lo[2] = (__bf16)f0.z; lo[3] = (__bf16)f0.w;
  lo[4] = (__bf16)f1.x; lo[5] = (__bf16)f1.y; lo[6] = (__bf16)f1.z; lo[7] = (__bf16)f1.w;
  hi[0] = (__bf16)f2.x; hi[1] = (__bf16)f2.y; hi[2] = (__bf16)f2.z; hi[3] = (__bf16)f2.w;
  hi[4] = (__bf16)f3.x; hi[5] = (__bf16)f3.y; hi[6] = (__bf16)f3.z; hi[7] = (__bf16)f3.w;
  *(bf16x8*)&dst[row][colb]     = lo;
  *(bf16x8*)&dst[row][colb + 8] = hi;
}

// -----------------------------------------------------------------------------
// Kernel A: fused Q-proj + KV-proj + flash attention.
// grid = 256 blocks: bid = (bt<<4) | (h<<1) | js   (16 bt x 8 heads x 2 j-splits)
// block = 512 threads = 8 waves: wave = (it<<1) | jsub   (4 q-tiles x 2 j-subsplits)
// Each wave maintains online softmax over its j-subset; partials to workspace.
// -----------------------------------------------------------------------------
__global__ __launch_bounds__(512, 2) void pa_attn(
    const float* __restrict__ tensor,   // [16][1024][128]
    const float* __restrict__ latents,  // [16][64][128]
    const float* __restrict__ Wq,       // [128][2048]
    const float* __restrict__ Wkv,      // [128][4096]
    float* __restrict__ Opart,          // [4][16][8][64][256]
    float* __restrict__ Mpart,          // [4][16][8][64]
    float* __restrict__ Lpart)          // [4][16][8][64]
{
  __shared__ __align__(16) __bf16 Xs[64][136];    // staged kv-input tile
  __shared__ __align__(16) __bf16 Qs[64][264];    // Q (scaled), [i][d]
  __shared__ __align__(16) __bf16 Ks[64][264];    // K tile, [j][d]
  __shared__ __align__(16) __bf16 Vts[256][72];   // V tile transposed, [d][j]
  __shared__ __align__(16) __bf16 Ps[8][16][40];  // per-wave P, [i][j_local]

  const int bid = blockIdx.x;
  const int bt  = bid >> 4;
  const int h   = (bid >> 1) & 7;
  const int js  = bid & 1;

  const int tid  = threadIdx.x;
  const int wave = tid >> 6;
  const int lane = tid & 63;
  const int l15  = lane & 15;
  const int lg   = lane >> 4;
  const int it   = wave >> 1;   // q-row tile (16 rows)
  const int jsub = wave & 1;    // j sub-split within the 64-row kv tile

  const float* latBT = latents + (size_t)bt * (64 * 128);
  const float* tenBT = tensor  + (size_t)bt * (1024 * 128);

  // ---------------- prologue: Q = latents @ Wq[:, h-slice] * SCALE -----------
  stage64x128(latBT, Xs, tid);
  __syncthreads();

  #pragma unroll
  for (int n = 0; n < 2; ++n) {
    const int nt = wave * 2 + n;                  // 0..15 across waves
    const int dcol = h * 256 + nt * 16 + l15;
    f32x4 acc[4] = {};
    #pragma unroll
    for (int kb = 0; kb < 4; ++kb) {
      const int c = kb * 32 + lg * 8;
      bf16x8 bf;
      #pragma unroll
      for (int r = 0; r < 8; ++r) bf[r] = (__bf16)Wq[(size_t)(c + r) * 2048 + dcol];
      #pragma unroll
      for (int mt = 0; mt < 4; ++mt) {
        bf16x8 af = *(const bf16x8*)&Xs[mt * 16 + l15][kb * 32 + lg * 8];
        acc[mt] = mfma16(af, bf, acc[mt]);
      }
    }
    #pragma unroll
    for (int mt = 0; mt < 4; ++mt)
      #pragma unroll
      for (int r = 0; r < 4; ++r)
        Qs[mt * 16 + lg * 4 + r][nt * 16 + l15] = (__bf16)(acc[mt][r] * SCALE);
  }

  // ---------------- load Wk/Wv B-fragments into registers (kept) -------------
  bf16x8 wk[2][4], wv[2][4];
  #pragma unroll
  for (int n = 0; n < 2; ++n) {
    const int dcol = h * 256 + (wave * 2 + n) * 16 + l15;
    #pragma unroll
    for (int kb = 0; kb < 4; ++kb) {
      const int c = kb * 32 + lg * 8;
      bf16x8 k8, v8;
      #pragma unroll
      for (int r = 0; r < 8; ++r) {
        k8[r] = (__bf16)Wkv[(size_t)(c + r) * 4096 + dcol];
        v8[r] = (__bf16)Wkv[(size_t)(c + r) * 4096 + 2048 + dcol];
      }
      wk[n][kb] = k8;
      wv[n][kb] = v8;
    }
  }
  __syncthreads();   // Qs ready; Xs free for tile staging

  // ---------------- flash loop over kv tiles ---------------------------------
  float mrow[4] = {-INFINITY, -INFINITY, -INFINITY, -INFINITY};
  float lrow[4] = {0.f, 0.f, 0.f, 0.f};
  f32x4 oacc[16] = {};

  const int t0 = js ? 9 : 0;
  const int t1 = js ? 17 : 9;
  for (int t = t0; t < t1; ++t) {
    // stage kv-input tile (tiles 0..15 = tensor, tile 16 = latents)
    const float* base = (t < 16) ? (tenBT + (size_t)t * 64 * 128) : latBT;
    stage64x128(base, Xs, tid);
    __syncthreads();   // staging done AND all waves done reading Ks/Vts of t-1

    // KV projection: this wave's 32 d-cols, all 64 j
    #pragma unroll
    for (int mt = 0; mt < 4; ++mt) {
      f32x4 ka[2] = {}, va[2] = {};
      #pragma unroll
      for (int kb = 0; kb < 4; ++kb) {
        bf16x8 af = *(const bf16x8*)&Xs[mt * 16 + l15][kb * 32 + lg * 8];
        #pragma unroll
        for (int n = 0; n < 2; ++n) {
          ka[n] = mfma16(af, wk[n][kb], ka[n]);
          va[n] = mfma16(af, wv[n][kb], va[n]);
        }
      }
      #pragma unroll
      for (int n = 0; n < 2; ++n) {
        const int d = (wave * 2 + n) * 16 + l15;
        const int j = mt * 16 + lg * 4;
        #pragma unroll
        for (int r = 0; r < 4; ++r) Ks[j + r][d] = (__bf16)ka[n][r];
        bf16x4 vp;
        vp[0] = (__bf16)va[n][0]; vp[1] = (__bf16)va[n][1];
        vp[2] = (__bf16)va[n][2]; vp[3] = (__bf16)va[n][3];
        *(bf16x4*)&Vts[d][j] = vp;   // transposed store: 4 consecutive j
      }
    }
    __syncthreads();   // K/V tile ready

    // S = Q @ K^T for (it, jsub): [16 i][32 j]
    f32x4 sacc[2] = {};
    #pragma unroll
    for (int kb = 0; kb < 8; ++kb) {
      bf16x8 qv = *(const bf16x8*)&Qs[it * 16 + l15][kb * 32 + lg * 8];
      #pragma unroll
      for (int jt = 0; jt < 2; ++jt) {
        bf16x8 kf = *(const bf16x8*)&Ks[jsub * 32 + jt * 16 + l15][kb * 32 + lg * 8];
        sacc[jt] = mfma16(qv, kf, sacc[jt]);
      }
    }

    // online softmax over this tile's 32 j (rows are lane-local: i = lg*4+r)
    float alr[4];
    #pragma unroll
    for (int r = 0; r < 4; ++r) {
      float v = fmaxf(sacc[0][r], sacc[1][r]);
      v = fmaxf(v, __shfl_xor(v, 1));
      v = fmaxf(v, __shfl_xor(v, 2));
      v = fmaxf(v, __shfl_xor(v, 4));
      v = fmaxf(v, __shfl_xor(v, 8));
      const float mn = fmaxf(mrow[r], v);
      const float al = expf(mrow[r] - mn);   // first tile: exp(-inf)=0
      const float p0 = expf(sacc[0][r] - mn);
      const float p1 = expf(sacc[1][r] - mn);
      sacc[0][r] = p0; sacc[1][r] = p1;
      float s = p0 + p1;
      s += __shfl_xor(s, 1);
      s += __shfl_xor(s, 2);
      s += __shfl_xor(s, 4);
      s += __shfl_xor(s, 8);
      lrow[r] = lrow[r] * al + s;
      mrow[r] = mn;
      alr[r] = al;
    }

    // write P (wave-private LDS), rescale O
    #pragma unroll
    for (int jt = 0; jt < 2; ++jt)
      #pragma unroll
      for (int r = 0; r < 4; ++r)
        Ps[wave][lg * 4 + r][jt * 16 + l15] = (__bf16)sacc[jt][r];

    #pragma unroll
    for (int dt = 0; dt < 16; ++dt) {
      oacc[dt][0] *= alr[0]; oacc[dt][1] *= alr[1];
      oacc[dt][2] *= alr[2]; oacc[dt][3] *= alr[3];
    }

    // wave-internal LDS producer->consumer fence (no block barrier needed)
    asm volatile("s_waitcnt lgkmcnt(0)" ::: "memory");

    bf16x8 pf = *(const bf16x8*)&Ps[wave][l15][lg * 8];
    #pragma unroll
    for (int dt = 0; dt < 16; ++dt) {
      bf16x8 vb = *(const bf16x8*)&Vts[dt * 16 + l15][jsub * 32 + lg * 8];
      oacc[dt] = mfma16(pf, vb, oacc[dt]);
    }
  }

  // ---------------- epilogue: write unnormalized partials --------------------
  const int jsplit = js * 2 + jsub;
  const size_t ob = ((((size_t)jsplit * 16 + bt) * 8 + h) * 64) * 256;
  #pragma unroll
  for (int dt = 0; dt < 16; ++dt)
    #pragma unroll
    for (int r = 0; r < 4; ++r)
      Opart[ob + (size_t)(it * 16 + lg * 4 + r) * 256 + dt * 16 + l15] = oacc[dt][r];

  const size_t mb = (((size_t)jsplit * 16 + bt) * 8 + h) * 64;
  if (l15 == 0) {
    #pragma unroll
    for (int r = 0; r < 4; ++r) {
      Mpart[mb + it * 16 + lg * 4 + r] = mrow[r];
      Lpart[mb + it * 16 + lg * 4 + r] = lrow[r];
    }
  }
}

// -----------------------------------------------------------------------------
// Kernel C: merge 4 softmax splits, then O_h @ Wo[h*256:(h+1)*256, :] with
// hi/lo bf16 split (3 MFMAs) and atomicAdd into the (zeroed) output.
// grid = 128 blocks: bid = (bt<<3) | h ; block = 256 threads = 4 waves.
// -----------------------------------------------------------------------------
__global__ __launch_bounds__(256, 2) void pa_merge_proj(
    const float* __restrict__ Opart, const float* __restrict__ Mpart,
    const float* __restrict__ Lpart, const float* __restrict__ Wo,
    float* __restrict__ out)
{
  __shared__ float alf[4][64];
  __shared__ __align__(16) __bf16 Oh[64][264];
  __shared__ __align__(16) __bf16 Ol[64][264];

  const int bid = blockIdx.x;
  const int bt = bid >> 3, h = bid & 7;
  const int tid = threadIdx.x;

  if (tid < 64) {
    const int i = tid;
    float m[4], L[4];
    #pragma unroll
    for (int s = 0; s < 4; ++s) {
      const size_t b = (((size_t)s * 16 + bt) * 8 + h) * 64 + i;
      m[s] = Mpart[b]; L[s] = Lpart[b];
    }
    const float mm = fmaxf(fmaxf(m[0], m[1]), fmaxf(m[2], m[3]));
    float a[4]; float den = 0.f;
    #pragma unroll
    for (int s = 0; s < 4; ++s) { a[s] = expf(m[s] - mm); den += a[s] * L[s]; }
    const float inv = 1.0f / den;
    #pragma unroll
    for (int s = 0; s < 4; ++s) alf[s][i] = a[s] * inv;
  }
  __syncthreads();

  // merge partials -> normalized O in hi/lo bf16
  #pragma unroll
  for (int k = 0; k < 16; ++k) {
    const int f = tid + k * 256;          // 0..4095 float4 slots
    const int i = f >> 6, d4 = f & 63;
    float vx = 0.f, vy = 0.f, vz = 0.f, vw = 0.f;
    #pragma unroll
    for (int s = 0; s < 4; ++s) {
      const float a = alf[s][i];
      const float4 v = *(const float4*)&Opart[(((size_t)s * 16 + bt) * 8 + h) * 16384 +
                                              (size_t)i * 256 + d4 * 4];
      vx += a * v.x; vy += a * v.y; vz += a * v.z; vw += a * v.w;
    }
    bf16x4 h4, l4;
    h4[0] = (__bf16)vx; h4[1] = (__bf16)vy; h4[2] = (__bf16)vz; h4[3] = (__bf16)vw;
    l4[0] = (__bf16)(vx - (float)h4[0]);
    l4[1] = (__bf16)(vy - (float)h4[1]);
    l4[2] = (__bf16)(vz - (float)h4[2]);
    l4[3] = (__bf16)(vw - (float)h4[3]);
    *(bf16x4*)&Oh[i][d4 * 4] = h4;
    *(bf16x4*)&Ol[i][d4 * 4] = l4;
  }
  __syncthreads();

  const int wave = tid >> 6, lane = tid & 63;
  const int l15 = lane & 15, lg = lane >> 4;
  f32x4 acc[4][2] = {};
  #pragma unroll
  for (int kb = 0; kb < 8; ++kb) {
    bf16x8 bh[2], bl[2];
    #pragma unroll
    for (int n = 0; n < 2; ++n) {
      const int ncol = (wave * 2 + n) * 16 + l15;
      #pragma unroll
      for (int r = 0; r < 8; ++r) {
        const float w = Wo[(size_t)(h * 256 + kb * 32 + lg * 8 + r) * 128 + ncol];
        const __bf16 wh = (__bf16)w;
        bh[n][r] = wh;
        bl[n][r] = (__bf16)(w - (float)wh);
      }
    }
    #pragma unroll
    for (int mt = 0; mt < 4; ++mt) {
      bf16x8 ah  = *(const bf16x8*)&Oh[mt * 16 + l15][kb * 32 + lg * 8];
      bf16x8 al8 = *(const bf16x8*)&Ol[mt * 16 + l15][kb * 32 + lg * 8];
      #pragma unroll
      for (int n = 0; n < 2; ++n) {
        acc[mt][n] = mfma16(ah,  bh[n], acc[mt][n]);
        acc[mt][n] = mfma16(ah,  bl[n], acc[mt][n]);
        acc[mt][n] = mfma16(al8, bh[n], acc[mt][n]);
      }
    }
  }
  #pragma unroll
  for (int mt = 0; mt < 4; ++mt)
    #pragma unroll
    for (int n = 0; n < 2; ++n)
      #pragma unroll
      for (int r = 0; r < 4; ++r)
        atomicAdd(&out[(size_t)bt * 8192 + (size_t)(mt * 16 + lg * 4 + r) * 128 +
                       (wave * 2 + n) * 16 + l15],
                  acc[mt][n][r]);
}

// -----------------------------------------------------------------------------
extern "C" void kernel_launch(void* const* d_in, const int* in_sizes, int n_in,
                              void* d_out, int out_size, void* d_ws, size_t ws_size,
                              hipStream_t stream) {
  const float* tensor  = (const float*)d_in[0];
  const float* latents = (const float*)d_in[1];
  const float* Wq      = (const float*)d_in[2];
  const float* Wkv     = (const float*)d_in[3];
  const float* Wo      = (const float*)d_in[4];
  float* out = (float*)d_out;

  float* Opart = (float*)d_ws;                               // 4*16*8*64*256 f32
  float* Mpart = Opart + (size_t)4 * 16 * 8 * 64 * 256;      // 4*16*8*64
  float* Lpart = Mpart + (size_t)4 * 16 * 8 * 64;

  hipMemsetAsync(d_out, 0, (size_t)out_size * sizeof(float), stream);
  pa_attn<<<256, 512, 0, stream>>>(tensor, latents, Wq, Wkv, Opart, Mpart, Lpart);
  pa_merge_proj<<<128, 256, 0, stream>>>(Opart, Mpart, Lpart, Wo, out);
}

// Round 5
// 128.081 us; speedup vs baseline: 1.0552x; 1.0552x over previous
//
#include <hip/hip_runtime.h>

typedef __bf16 bf16x8 __attribute__((ext_vector_type(8)));
typedef __bf16 bf16x4 __attribute__((ext_vector_type(4)));
typedef float  f32x4  __attribute__((ext_vector_type(4)));

// scale * log2(e): softmax computed in base-2 domain
#define SCALE2 (0.08838834764831845f * 1.4426950408889634f)

__device__ __forceinline__ f32x4 mfma16(bf16x8 a, bf16x8 b, f32x4 c) {
  return __builtin_amdgcn_mfma_f32_16x16x32_bf16(a, b, c, 0, 0, 0);
}

// ---- split staging: issue loads early (T14), convert+write late -------------
__device__ __forceinline__ void stage_load(const float* __restrict__ src, int tid,
                                           float4 (&r)[4]) {
  const float4* s4 = (const float4*)(src + (size_t)(tid >> 3) * 128 + ((tid & 7) << 4));
  r[0] = s4[0]; r[1] = s4[1]; r[2] = s4[2]; r[3] = s4[3];
}
__device__ __forceinline__ void stage_write(const float4 (&r)[4], __bf16 (*dst)[136],
                                            int tid) {
  const int row = tid >> 3, colb = (tid & 7) << 4;
  bf16x8 lo, hi;
  lo[0] = (__bf16)r[0].x; lo[1] = (__bf16)r[0].y; lo[2] = (__bf16)r[0].z; lo[3] = (__bf16)r[0].w;
  lo[4] = (__bf16)r[1].x; lo[5] = (__bf16)r[1].y; lo[6] = (__bf16)r[1].z; lo[7] = (__bf16)r[1].w;
  hi[0] = (__bf16)r[2].x; hi[1] = (__bf16)r[2].y; hi[2] = (__bf16)r[2].z; hi[3] = (__bf16)r[2].w;
  hi[4] = (__bf16)r[3].x; hi[5] = (__bf16)r[3].y; hi[6] = (__bf16)r[3].z; hi[7] = (__bf16)r[3].w;
  *(bf16x8*)&dst[row][colb]     = lo;
  *(bf16x8*)&dst[row][colb + 8] = hi;
}

// -----------------------------------------------------------------------------
// Kernel A: fused Q-proj + KV-proj + flash attention. Q held in registers;
// async-split staging hides HBM latency under KVproj+QK.
// grid = 256: bid = (bt<<4)|(h<<1)|js ; block = 512 = 8 waves: wave=(it<<1)|jsub
// js=0 processes ten[0..8] (9 tiles); js=1 processes lat + ten[9..15] (8 tiles)
// -----------------------------------------------------------------------------
__global__ __launch_bounds__(512, 2) void pa_attn(
    const float* __restrict__ tensor,   // [16][1024][128]
    const float* __restrict__ latents,  // [16][64][128]
    const float* __restrict__ Wq,       // [128][2048]
    const float* __restrict__ Wkv,      // [128][4096]
    __bf16* __restrict__ Opart,         // [4][16][8][64][256] bf16
    float* __restrict__ Mpart,          // [4][16][8][64]  (base-2 max)
    float* __restrict__ Lpart)          // [4][16][8][64]
{
  __shared__ __align__(16) __bf16 Xs[64][136];    // staged kv-input tile
  __shared__ __align__(16) __bf16 Ks[64][264];    // K tile [j][d]; Q-temp in prologue
  __shared__ __align__(16) __bf16 Vts[256][72];   // V transposed [d][j]
  __shared__ __align__(16) __bf16 Ps[8][16][40];  // per-wave P

  const int bid = blockIdx.x;
  const int bt  = bid >> 4;
  const int h   = (bid >> 1) & 7;
  const int js  = bid & 1;

  const int tid  = threadIdx.x;
  const int wave = tid >> 6;
  const int lane = tid & 63;
  const int l15  = lane & 15;
  const int lg   = lane >> 4;
  const int it   = wave >> 1;
  const int jsub = wave & 1;

  const float* latBT = latents + (size_t)bt * (64 * 128);
  const float* tenBT = tensor  + (size_t)bt * (1024 * 128);

  // ---------------- prologue: stage latents, Q-proj into Ks(temp) ------------
  {
    float4 st[4];
    stage_load(latBT, tid, st);
    stage_write(st, Xs, tid);
  }
  __syncthreads();

  #pragma unroll
  for (int n = 0; n < 2; ++n) {
    const int nt = wave * 2 + n;
    const int dcol = h * 256 + nt * 16 + l15;
    f32x4 acc[4] = {};
    #pragma unroll
    for (int kb = 0; kb < 4; ++kb) {
      const int c = kb * 32 + lg * 8;
      bf16x8 bf;
      #pragma unroll
      for (int r = 0; r < 8; ++r) bf[r] = (__bf16)Wq[(size_t)(c + r) * 2048 + dcol];
      #pragma unroll
      for (int mt = 0; mt < 4; ++mt) {
        bf16x8 af = *(const bf16x8*)&Xs[mt * 16 + l15][kb * 32 + lg * 8];
        acc[mt] = mfma16(af, bf, acc[mt]);
      }
    }
    #pragma unroll
    for (int mt = 0; mt < 4; ++mt)
      #pragma unroll
      for (int r = 0; r < 4; ++r)
        Ks[mt * 16 + lg * 4 + r][nt * 16 + l15] = (__bf16)(acc[mt][r] * SCALE2);
  }

  // Wk/Wv B-fragments in registers (kept for whole kernel)
  bf16x8 wk[2][4], wv[2][4];
  #pragma unroll
  for (int n = 0; n < 2; ++n) {
    const int dcol = h * 256 + (wave * 2 + n) * 16 + l15;
    #pragma unroll
    for (int kb = 0; kb < 4; ++kb) {
      const int c = kb * 32 + lg * 8;
      bf16x8 k8, v8;
      #pragma unroll
      for (int r = 0; r < 8; ++r) {
        k8[r] = (__bf16)Wkv[(size_t)(c + r) * 4096 + dcol];
        v8[r] = (__bf16)Wkv[(size_t)(c + r) * 4096 + 2048 + dcol];
      }
      wk[n][kb] = k8;
      wv[n][kb] = v8;
    }
  }
  __syncthreads();   // Q-temp ready in Ks; Xs reads done

  // Q fragments to registers (frees Ks for K tiles)
  bf16x8 qf[8];
  #pragma unroll
  for (int kb = 0; kb < 8; ++kb)
    qf[kb] = *(const bf16x8*)&Ks[it * 16 + l15][kb * 32 + lg * 8];

  // first kv tile: js=0 stages tensor tile 0; js=1 reuses latents already in Xs
  {
    float4 st[4];
    if (js == 0) stage_load(tenBT, tid, st);
    __syncthreads();                 // qf reads drained; Ks/Xs free
    if (js == 0) {
      stage_write(st, Xs, tid);
      __syncthreads();
    }
  }

  // ---------------- flash loop -----------------------------------------------
  float mrow[4] = {-INFINITY, -INFINITY, -INFINITY, -INFINITY};
  float lrow[4] = {0.f, 0.f, 0.f, 0.f};
  f32x4 oacc[16] = {};

  const int NT = js ? 8 : 9;          // js=1: lat + ten[9..15]; js=0: ten[0..8]
  for (int t8 = 0; t8 < NT; ++t8) {
    const bool pf = (t8 < NT - 1);
    float4 st[4];
    if (pf) stage_load(tenBT + (size_t)((js ? 9 : 1) + t8) * (64 * 128), tid, st);

    // KV projection: reads Xs(t), writes Ks/Vts(t)
    #pragma unroll
    for (int mt = 0; mt < 4; ++mt) {
      f32x4 ka[2] = {}, va[2] = {};
      #pragma unroll
      for (int kb = 0; kb < 4; ++kb) {
        bf16x8 af = *(const bf16x8*)&Xs[mt * 16 + l15][kb * 32 + lg * 8];
        #pragma unroll
        for (int n = 0; n < 2; ++n) {
          ka[n] = mfma16(af, wk[n][kb], ka[n]);
          va[n] = mfma16(af, wv[n][kb], va[n]);
        }
      }
      #pragma unroll
      for (int n = 0; n < 2; ++n) {
        const int d = (wave * 2 + n) * 16 + l15;
        const int j = mt * 16 + lg * 4;
        #pragma unroll
        for (int r = 0; r < 4; ++r) Ks[j + r][d] = (__bf16)ka[n][r];
        bf16x4 vp;
        vp[0] = (__bf16)va[n][0]; vp[1] = (__bf16)va[n][1];
        vp[2] = (__bf16)va[n][2]; vp[3] = (__bf16)va[n][3];
        *(bf16x4*)&Vts[d][j] = vp;
      }
    }
    __syncthreads();   // K/V(t) ready; Xs(t) consumed by all waves

    // S = Q @ K^T (Q from registers)
    f32x4 sacc[2] = {};
    #pragma unroll
    for (int kb = 0; kb < 8; ++kb) {
      #pragma unroll
      for (int jt = 0; jt < 2; ++jt) {
        bf16x8 kf = *(const bf16x8*)&Ks[jsub * 32 + jt * 16 + l15][kb * 32 + lg * 8];
        sacc[jt] = mfma16(qf[kb], kf, sacc[jt]);
      }
    }

    // online softmax, base-2 domain (rows i = lg*4+r lane-local)
    float alr[4];
    #pragma unroll
    for (int r = 0; r < 4; ++r) {
      float v = fmaxf(sacc[0][r], sacc[1][r]);
      v = fmaxf(v, __shfl_xor(v, 1));
      v = fmaxf(v, __shfl_xor(v, 2));
      v = fmaxf(v, __shfl_xor(v, 4));
      v = fmaxf(v, __shfl_xor(v, 8));
      const float mn = fmaxf(mrow[r], v);
      const float al = exp2f(mrow[r] - mn);
      const float p0 = exp2f(sacc[0][r] - mn);
      const float p1 = exp2f(sacc[1][r] - mn);
      sacc[0][r] = p0; sacc[1][r] = p1;
      float s = p0 + p1;
      s += __shfl_xor(s, 1);
      s += __shfl_xor(s, 2);
      s += __shfl_xor(s, 4);
      s += __shfl_xor(s, 8);
      lrow[r] = lrow[r] * al + s;
      mrow[r] = mn;
      alr[r] = al;
    }

    // write P; async-stage LDS-write for tile t+1; rescale O
    #pragma unroll
    for (int jt = 0; jt < 2; ++jt)
      #pragma unroll
      for (int r = 0; r < 4; ++r)
        Ps[wave][lg * 4 + r][jt * 16 + l15] = (__bf16)sacc[jt][r];

    if (pf) stage_write(st, Xs, tid);   // Xs(t) reads were pre-barrier: safe

    #pragma unroll
    for (int dt = 0; dt < 16; ++dt) {
      oacc[dt][0] *= alr[0]; oacc[dt][1] *= alr[1];
      oacc[dt][2] *= alr[2]; oacc[dt][3] *= alr[3];
    }

    asm volatile("s_waitcnt lgkmcnt(0)" ::: "memory");

    bf16x8 pfr = *(const bf16x8*)&Ps[wave][l15][lg * 8];
    #pragma unroll
    for (int dt = 0; dt < 16; ++dt) {
      bf16x8 vb = *(const bf16x8*)&Vts[dt * 16 + l15][jsub * 32 + lg * 8];
      oacc[dt] = mfma16(pfr, vb, oacc[dt]);
    }
    __syncthreads();   // K/V(t) reads done; Xs(t+1) visible to all
  }

  // ---------------- epilogue: unnormalized partials (bf16) -------------------
  const int jsplit = js * 2 + jsub;
  const size_t ob = ((((size_t)jsplit * 16 + bt) * 8 + h) * 64) * 256;
  #pragma unroll
  for (int dt = 0; dt < 16; ++dt)
    #pragma unroll
    for (int r = 0; r < 4; ++r)
      Opart[ob + (size_t)(it * 16 + lg * 4 + r) * 256 + dt * 16 + l15] =
          (__bf16)oacc[dt][r];

  const size_t mb = (((size_t)jsplit * 16 + bt) * 8 + h) * 64;
  if (l15 == 0) {
    #pragma unroll
    for (int r = 0; r < 4; ++r) {
      Mpart[mb + it * 16 + lg * 4 + r] = mrow[r];
      Lpart[mb + it * 16 + lg * 4 + r] = lrow[r];
    }
  }
}

// -----------------------------------------------------------------------------
// Kernel B: merge 4 splits + project through Wo[h-slice] (hi/lo bf16 split).
// Atomic-free: writes per-head partials to ws. grid = 256: bid=(bt<<4)|(h<<1)|ch
// -----------------------------------------------------------------------------
__global__ __launch_bounds__(256, 2) void pa_proj(
    const __bf16* __restrict__ Opart, const float* __restrict__ Mpart,
    const float* __restrict__ Lpart, const float* __restrict__ Wo,
    float* __restrict__ part)           // [8][16][64][128] f32
{
  __shared__ float alf[4][64];
  __shared__ __align__(16) __bf16 Oh[64][264];
  __shared__ __align__(16) __bf16 Ol[64][264];

  const int bid = blockIdx.x;
  const int bt = bid >> 4, h = (bid >> 1) & 7, ch = bid & 1;
  const int tid = threadIdx.x;

  if (tid < 64) {
    const int i = tid;
    float m[4], L[4];
    #pragma unroll
    for (int s = 0; s < 4; ++s) {
      const size_t b = (((size_t)s * 16 + bt) * 8 + h) * 64 + i;
      m[s] = Mpart[b]; L[s] = Lpart[b];
    }
    const float mm = fmaxf(fmaxf(m[0], m[1]), fmaxf(m[2], m[3]));
    float a[4]; float den = 0.f;
    #pragma unroll
    for (int s = 0; s < 4; ++s) { a[s] = exp2f(m[s] - mm); den += a[s] * L[s]; }
    const float inv = 1.0f / den;
    #pragma unroll
    for (int s = 0; s < 4; ++s) alf[s][i] = a[s] * inv;
  }
  __syncthreads();

  // merge 4 partials -> normalized O as hi/lo bf16
  #pragma unroll
  for (int k = 0; k < 8; ++k) {
    const int f = tid + k * 256;          // 2048 bf16x8 slots
    const int i = f >> 5, d8 = f & 31;
    float v[8] = {0.f, 0.f, 0.f, 0.f, 0.f, 0.f, 0.f, 0.f};
    #pragma unroll
    for (int s = 0; s < 4; ++s) {
      const float a = alf[s][i];
      bf16x8 o8 = *(const bf16x8*)&Opart[(((size_t)s * 16 + bt) * 8 + h) * 16384 +
                                         (size_t)i * 256 + d8 * 8];
      #pragma unroll
      for (int e = 0; e < 8; ++e) v[e] += a * (float)o8[e];
    }
    bf16x8 h8, l8;
    #pragma unroll
    for (int e = 0; e < 8; ++e) {
      h8[e] = (__bf16)v[e];
      l8[e] = (__bf16)(v[e] - (float)h8[e]);
    }
    *(bf16x8*)&Oh[i][d8 * 8] = h8;
    *(bf16x8*)&Ol[i][d8 * 8] = l8;
  }
  __syncthreads();

  const int wave = tid >> 6, lane = tid & 63;
  const int l15 = lane & 15, lg = lane >> 4;
  const int ncol = ch * 64 + wave * 16 + l15;   // global out column
  f32x4 acc[4] = {};
  #pragma unroll
  for (int kb = 0; kb < 8; ++kb) {
    bf16x8 bh, bl;
    #pragma unroll
    for (int r = 0; r < 8; ++r) {
      const float w = Wo[(size_t)(h * 256 + kb * 32 + lg * 8 + r) * 128 + ncol];
      const __bf16 wh = (__bf16)w;
      bh[r] = wh;
      bl[r] = (__bf16)(w - (float)wh);
    }
    #pragma unroll
    for (int mt = 0; mt < 4; ++mt) {
      bf16x8 ah  = *(const bf16x8*)&Oh[mt * 16 + l15][kb * 32 + lg * 8];
      bf16x8 al8 = *(const bf16x8*)&Ol[mt * 16 + l15][kb * 32 + lg * 8];
      acc[mt] = mfma16(ah,  bh, acc[mt]);
      acc[mt] = mfma16(ah,  bl, acc[mt]);
      acc[mt] = mfma16(al8, bh, acc[mt]);
    }
  }
  const size_t pb = ((size_t)h * 16 + bt) * 8192;
  #pragma unroll
  for (int mt = 0; mt < 4; ++mt)
    #pragma unroll
    for (int r = 0; r < 4; ++r)
      part[pb + (size_t)(mt * 16 + lg * 4 + r) * 128 + ncol] = acc[mt][r];
}

// -----------------------------------------------------------------------------
// Kernel C: sum 8 heads -> out (fully overwrites d_out; no memset needed)
// -----------------------------------------------------------------------------
__global__ __launch_bounds__(256) void pa_reduce(const float* __restrict__ part,
                                                 float* __restrict__ out) {
  const int idx = blockIdx.x * 256 + threadIdx.x;   // float4 index, 32768 total
  const f32x4* p4 = (const f32x4*)part;
  f32x4 s = p4[idx];
  #pragma unroll
  for (int h = 1; h < 8; ++h) s += p4[(size_t)h * 32768 + idx];
  ((f32x4*)out)[idx] = s;
}

// -----------------------------------------------------------------------------
extern "C" void kernel_launch(void* const* d_in, const int* in_sizes, int n_in,
                              void* d_out, int out_size, void* d_ws, size_t ws_size,
                              hipStream_t stream) {
  const float* tensor  = (const float*)d_in[0];
  const float* latents = (const float*)d_in[1];
  const float* Wq      = (const float*)d_in[2];
  const float* Wkv     = (const float*)d_in[3];
  const float* Wo      = (const float*)d_in[4];
  float* out = (float*)d_out;

  __bf16* Opart = (__bf16*)d_ws;                              // 8,388,608 bf16 = 16MB
  float* Mpart = (float*)(Opart + (size_t)4 * 16 * 8 * 64 * 256);  // 32768 f32
  float* Lpart = Mpart + (size_t)4 * 16 * 8 * 64;                  // 32768 f32
  float* part  = Lpart + (size_t)4 * 16 * 8 * 64;                  // 1,048,576 f32

  pa_attn<<<256, 512, 0, stream>>>(tensor, latents, Wq, Wkv, Opart, Mpart, Lpart);
  pa_proj<<<256, 256, 0, stream>>>(Opart, Mpart, Lpart, Wo, part);
  pa_reduce<<<128, 256, 0, stream>>>(part, out);
}